// Round 7
// baseline (2177.723 us; speedup 1.0000x reference)
//
#include <hip/hip_runtime.h>
#include <hip/hip_bf16.h>
#include <math.h>

// SplineCNN on MI355X — round 7.
// Prep: counting-sort 32B edge records {basis4*invdeg, src, kpack, dst} by dst.
// Layer phase A: lane-parallel edges — lane = (edge-in-batch, ch-group-of-4);
// one dwordx4 x-gather per edge, 16 fma + 16 ds_add_f32 per lane-edge into an
// f32 LDS accumulator AL[t][k][ch] (k-row stride KR % 4 != 0 for bank spread).
// Atomics make all collisions correct; 3-stage pipeline (meta+2, xv+1).
// Repack: register-staged in-place AL(f32) -> ACC(bf16 MFMA layout).
// Phase B: split-K MFMA 16x16x32_bf16 (parity g) + LDS reduce, bias+ELU.

typedef __attribute__((ext_vector_type(8))) short bf16x8;
typedef __attribute__((ext_vector_type(4))) float f32x4;

// ---------------------------------------------------------------- preprocessing

__global__ void hist_kernel(const int* __restrict__ ei, int* __restrict__ deg, int E) {
    int e = blockIdx.x * blockDim.x + threadIdx.x;
    if (e < E) atomicAdd(&deg[ei[E + e]], 1);
}

__global__ __launch_bounds__(256) void scan_kernel(const int* __restrict__ deg,
                                                   int* __restrict__ row_start,
                                                   int* __restrict__ cursor,
                                                   float* __restrict__ invdeg, int n) {
    __shared__ int wsum[4];
    int tid = threadIdx.x, lane = tid & 63, wave = tid >> 6;
    int carry = 0;
    for (int base = 0; base < n; base += 2048) {
        int idx0 = base + tid * 8;
        int v[8], pre[8];
        int s = 0;
        #pragma unroll
        for (int u = 0; u < 8; ++u) {
            int id = idx0 + u;
            v[u] = (id < n) ? deg[id] : 0;
            pre[u] = s;
            s += v[u];
        }
        int inc = s;
        #pragma unroll
        for (int off = 1; off < 64; off <<= 1) {
            int t = __shfl_up(inc, off);
            if (lane >= off) inc += t;
        }
        if (lane == 63) wsum[wave] = inc;
        __syncthreads();
        int woff = 0;
        for (int w2 = 0; w2 < wave; ++w2) woff += wsum[w2];
        int tot = wsum[0] + wsum[1] + wsum[2] + wsum[3];
        int eb = carry + woff + inc - s;
        #pragma unroll
        for (int u = 0; u < 8; ++u) {
            int id = idx0 + u;
            if (id < n) {
                int rs = eb + pre[u];
                row_start[id] = rs;
                cursor[id] = rs;
                invdeg[id] = 1.0f / fmaxf((float)v[u], 1.0f);
            }
        }
        carry += tot;
        __syncthreads();
    }
    if (tid == 0) row_start[n] = carry;
}

// Edge record: 32B = float4 basis (pre-scaled by 1/deg[dst]) + {src, kpack, dst, 0}
__global__ void scatter_kernel(const int* __restrict__ ei, const float* __restrict__ pseudo,
                               const float* __restrict__ invdeg, int* __restrict__ cursor,
                               float4* __restrict__ edges, int E) {
    int e = blockIdx.x * blockDim.x + threadIdx.x;
    if (e >= E) return;
    int src = ei[e], dst = ei[E + e];
    float p0 = pseudo[2 * e], p1 = pseudo[2 * e + 1];
    float v0 = fminf(fmaxf(p0, 0.f), 1.f) * 4.f;
    float v1 = fminf(fmaxf(p1, 0.f), 1.f) * 4.f;
    int k00 = min((int)floorf(v0), 3);
    int k01 = min((int)floorf(v1), 3);
    float f0 = v0 - (float)k00, f1 = v1 - (float)k01;
    float g0 = 1.f - f0, g1 = 1.f - f1;
    float sc = invdeg[dst];
    float4 b;
    b.x = g0 * g1 * sc;
    b.y = g0 * f1 * sc;
    b.z = f0 * g1 * sc;
    b.w = f0 * f1 * sc;
    int i00 = k00 * 5 + k01;
    unsigned ip = (unsigned)i00 | ((unsigned)(i00 + 1) << 8) |
                  ((unsigned)(i00 + 5) << 16) | ((unsigned)(i00 + 6) << 24);
    int pos = atomicAdd(&cursor[dst], 1);
    edges[pos * 2] = b;
    float4 m;
    m.x = __int_as_float(src);
    m.y = __uint_as_float(ip);
    m.z = __int_as_float(dst);
    m.w = 0.f;
    edges[pos * 2 + 1] = m;
}

// Wt[o][KW] bf16 from W[k][i][o] f32 (k=25 -> root), zero for kk >= 26*Cin.
template <int Cin, int Cout, int KW>
__global__ void wprep_kernel(const float* __restrict__ W, const float* __restrict__ root,
                             __hip_bfloat16* __restrict__ Wt) {
    int idx = blockIdx.x * 256 + threadIdx.x;
    if (idx >= Cout * KW) return;
    int o = idx / KW, kk = idx - o * KW;
    float v = 0.f;
    if (kk < 26 * Cin) {
        int k = kk / Cin, i = kk - k * Cin;
        v = (k < 25) ? W[(k * Cin + i) * Cout + o] : root[i * Cout + o];
    }
    Wt[idx] = __float2bfloat16(v);
}

// ---------------------------------------------------------------- fused layer

template <int Cin, int Cout, int T, int KR>
__global__ __launch_bounds__(512, 4) void layer_kernel(
        const float* __restrict__ xin, const __hip_bfloat16* __restrict__ Wt,
        const float* __restrict__ bias, const int* __restrict__ row_start,
        const float4* __restrict__ edges, float* __restrict__ xout, int nNodes) {
    constexpr int KW_RAW = 26 * Cin;
    constexpr int KW = (KW_RAW + 31) & ~31;     // MFMA K extent (zero-padded)
    constexpr int ST = KW + 8;                  // bf16 row stride
    constexpr int S_AL = 26 * KR;               // f32 accumulator node stride
    constexpr int AL_DW = T * S_AL;
    constexpr int LPE = Cin / 4;                // lanes per edge
    constexpr int EB = 64 / LPE;                // edges per batch per wave
    constexpr int NS = KW / 32;                 // MFMA K-slices
    constexpr int MT = (T >= 16) ? T / 16 : 1;
    constexpr int NT = Cout / 16;
    static_assert(MT * NT == 4, "4 (mt,nt) tiles");
    constexpr int RS = Cout + 4;
    static_assert(T * ST <= AL_DW * 2, "bf16 acc fits in AL footprint");
    static_assert(KR % 4 != 0, "combo bank decorrelation");

    __shared__ __align__(16) float ldsf[AL_DW];
    __hip_bfloat16* accb = (__hip_bfloat16*)ldsf;

    const int tid = threadIdx.x;
    const int node0 = blockIdx.x * T;
    const int wave = tid >> 6, lane = tid & 63;
    const int g = wave >> 2, w4 = wave & 3;
    const int e_in = lane / LPE;                 // edge within batch
    const int c4 = lane % LPE;                   // ch-group
    const int ch0 = c4 * 4;
    const int r16 = lane & 15, g8 = lane >> 4;
    const int mt = w4 / NT, nt = w4 % NT;

    // ---- zero AL
    for (int p = tid; p < AL_DW / 2; p += 512)
        ((uint2*)ldsf)[p] = make_uint2(0u, 0u);
    __syncthreads();
    // ---- self features at k=25 (edges only target k<25 -> disjoint with atomics)
    for (int p = tid; p < T * Cin; p += 512) {
        int t = p / Cin, i = p - t * Cin;
        int n = node0 + t;
        if (n < nNodes) ldsf[t * S_AL + 25 * KR + i] = xin[n * Cin + i];
    }

    // ---- phase A: lane-parallel edges, 3-stage pipeline, LDS f32 atomics
    {
        const int e0 = row_start[node0];
        const int e1 = row_start[min(node0 + T, nNodes)];
        int q = e0 + wave * EB;                  // wave-uniform batch start
        if (q < e1) {
            const int plast = e1 - 1;
            int pc = min(q + e_in, plast);
            float4 bC = edges[2 * pc], mC = edges[2 * pc + 1];
            int qn = q + 8 * EB;
            int pn = min(qn + e_in, plast);
            float4 bN = edges[2 * pn], mN = edges[2 * pn + 1];
            float4 xvC = *(const float4*)(xin + __float_as_int(mC.x) * Cin + ch0);
            while (true) {
                int qn2 = qn + 8 * EB;
                int pn2 = min(qn2 + e_in, plast);
                float4 bN2 = edges[2 * pn2], mN2 = edges[2 * pn2 + 1];
                float4 xvN = *(const float4*)(xin + __float_as_int(mN.x) * Cin + ch0);
                if (q + e_in < e1) {
                    int t = __float_as_int(mC.z) - node0;
                    unsigned ip = (unsigned)__float_as_int(mC.y);
                    float* abase = ldsf + t * S_AL + ch0;
                    #pragma unroll
                    for (int j = 0; j < 4; ++j) {
                        int k = (ip >> (8 * j)) & 255;
                        float bj = (j == 0) ? bC.x : (j == 1) ? bC.y : (j == 2) ? bC.z : bC.w;
                        float* a = abase + k * KR;
                        atomicAdd(a + 0, bj * xvC.x);
                        atomicAdd(a + 1, bj * xvC.y);
                        atomicAdd(a + 2, bj * xvC.z);
                        atomicAdd(a + 3, bj * xvC.w);
                    }
                }
                q = qn; qn = qn2;
                bC = bN; mC = mN; xvC = xvN;
                bN = bN2; mN = mN2;
                if (q >= e1) break;
            }
        }
    }
    __syncthreads();

    // ---- repack: AL f32 -> ACC bf16 (in place, register staged)
    {
        constexpr int THN = 512 / T;             // threads per node
        static_assert(THN == Cin || THN == 2 * Cin, "repack mapping");
        constexpr int QR = (THN == Cin) ? 26 : 13;
        const int t_r = tid / THN;
        const int sub = tid % THN;
        const int ch_r = sub % Cin;
        const int kb = (THN == Cin) ? 0 : (sub / Cin) * 13;
        float st[QR];
        #pragma unroll
        for (int q2 = 0; q2 < QR; ++q2)
            st[q2] = ldsf[t_r * S_AL + (kb + q2) * KR + ch_r];
        __syncthreads();
        #pragma unroll
        for (int q2 = 0; q2 < QR; ++q2)
            accb[t_r * ST + (kb + q2) * Cin + ch_r] = __float2bfloat16(st[q2]);
        if constexpr (KW > KW_RAW) {
            for (int p = tid; p < T * (KW - KW_RAW); p += 512) {
                int t2 = p / (KW - KW_RAW), kk = KW_RAW + p % (KW - KW_RAW);
                accb[t2 * ST + kk] = __float2bfloat16(0.f);
            }
        }
    }
    __syncthreads();

    // ---- phase B: split-K MFMA (slice parity = g)
    f32x4 dacc = {0.f, 0.f, 0.f, 0.f};
    {
        const __hip_bfloat16* wp = Wt + (size_t)(nt * 16 + r16) * KW;
        const __hip_bfloat16* ap = accb + (mt * 16 + r16) * ST;
        #pragma unroll
        for (int jj = 0; jj < (NS + 1) / 2; ++jj) {
            int s = 2 * jj + g;
            if (s < NS) {
                bf16x8 af = *(const bf16x8*)(ap + s * 32 + g8 * 8);
                bf16x8 bf = *(const bf16x8*)(wp + s * 32 + g8 * 8);
                dacc = __builtin_amdgcn_mfma_f32_16x16x32_bf16(af, bf, dacc, 0, 0, 0);
            }
        }
    }
    __syncthreads();
    float* red = ldsf;
    if (g == 1) {
        #pragma unroll
        for (int j = 0; j < 4; ++j)
            red[(mt * 16 + g8 * 4 + j) * RS + nt * 16 + r16] = dacc[j];
    }
    __syncthreads();
    if (g == 0) {
        const int o = nt * 16 + r16;
        const float bo = bias[o];
        #pragma unroll
        for (int j = 0; j < 4; ++j) {
            int row = mt * 16 + g8 * 4 + j;
            int n = node0 + row;
            if (row < T && n < nNodes) {
                float v = dacc[j] + red[row * RS + o] + bo;
                v = (v > 0.f) ? v : expm1f(v);
                xout[n * Cout + o] = v;
            }
        }
    }
}

// ---------------------------------------------------------------- pooling + head

__global__ void pool_kernel(const float* __restrict__ h, const int* __restrict__ batch,
                            float* __restrict__ pooled, float* __restrict__ cnt, int n) {
    int gw = (blockIdx.x * blockDim.x + threadIdx.x) >> 6;
    int lane = threadIdx.x & 63;
    int nw = (gridDim.x * blockDim.x) >> 6;
    int per = (n + nw - 1) / nw;
    int n0 = gw * per, n1 = min(n0 + per, n);
    if (n0 >= n1) return;
    int cur = batch[n0];
    float s = 0.f, c = 0.f;
    for (int nn = n0; nn < n1; ++nn) {
        int g = batch[nn];
        if (g != cur) {
            atomicAdd(&pooled[cur * 64 + lane], s);
            if (lane == 0) atomicAdd(&cnt[cur], c);
            s = 0.f; c = 0.f; cur = g;
        }
        s += h[nn * 64 + lane];
        c += 1.f;
    }
    atomicAdd(&pooled[cur * 64 + lane], s);
    if (lane == 0) atomicAdd(&cnt[cur], c);
}

__global__ __launch_bounds__(128) void head_kernel(const float* __restrict__ pooled,
                                                   const float* __restrict__ cnt,
                                                   const float* __restrict__ fcw,
                                                   const float* __restrict__ fcb,
                                                   float* __restrict__ outp, int G) {
    int g = threadIdx.x;
    if (g >= G) return;
    float inv = 1.f / fmaxf(cnt[g], 1.f);
    float l[30];
    float m = -1e30f;
    #pragma unroll
    for (int j = 0; j < 30; ++j) {
        float s = fcb[j];
        for (int i = 0; i < 64; ++i) s += pooled[g * 64 + i] * inv * fcw[i * 30 + j];
        l[j] = s;
        m = fmaxf(m, s);
    }
    float lse = 0.f;
    #pragma unroll
    for (int j = 0; j < 30; ++j) lse += expf(l[j] - m);
    lse = logf(lse);
    #pragma unroll
    for (int j = 0; j < 30; ++j) outp[g * 30 + j] = l[j] - m - lse;
}

// ---------------------------------------------------------------- launch

extern "C" void kernel_launch(void* const* d_in, const int* in_sizes, int n_in,
                              void* d_out, int out_size, void* d_ws, size_t ws_size,
                              hipStream_t stream) {
    const float* x = (const float*)d_in[0];
    const int* ei = (const int*)d_in[1];
    const float* ps = (const float*)d_in[2];
    const int* batch = (const int*)d_in[3];
    const float *w1 = (const float*)d_in[4], *r1 = (const float*)d_in[5], *b1 = (const float*)d_in[6];
    const float *w2 = (const float*)d_in[7], *r2 = (const float*)d_in[8], *b2 = (const float*)d_in[9];
    const float *w3 = (const float*)d_in[10], *r3 = (const float*)d_in[11], *b3 = (const float*)d_in[12];
    const float *fcw = (const float*)d_in[13], *fcb = (const float*)d_in[14];
    float* outp = (float*)d_out;

    const int nN = in_sizes[0] / 8;  // 50000
    const int E = in_sizes[1] / 2;   // 800000
    const int G = out_size / 30;     // 128

    char* wsb = (char*)d_ws;
    size_t off = 0;
    auto alloc = [&](size_t b) -> char* {
        char* p = wsb + off;
        off = (off + b + 255) & ~(size_t)255;
        return p;
    };
    int* deg = (int*)alloc((size_t)nN * 4);
    int* row_start = (int*)alloc((size_t)(nN + 1) * 4);
    int* cursor = (int*)alloc((size_t)nN * 4);
    float* invdeg = (float*)alloc((size_t)nN * 4);
    float4* edges = (float4*)alloc((size_t)E * 32);
    __hip_bfloat16* wt1 = (__hip_bfloat16*)alloc((size_t)32 * 224 * 2);
    __hip_bfloat16* wt2 = (__hip_bfloat16*)alloc((size_t)64 * 832 * 2);
    __hip_bfloat16* wt3 = (__hip_bfloat16*)alloc((size_t)64 * 1664 * 2);
    float* h1 = (float*)alloc((size_t)nN * 32 * 4);
    float* h2 = (float*)alloc((size_t)nN * 64 * 4);
    float* h3 = (float*)alloc((size_t)nN * 64 * 4);
    float* pooled = (float*)alloc((size_t)G * 64 * 4);
    float* cnt = (float*)alloc((size_t)G * 4);
    (void)ws_size;

    hipMemsetAsync(deg, 0, (size_t)nN * 4, stream);
    hipMemsetAsync(pooled, 0, (size_t)G * 64 * 4, stream);
    hipMemsetAsync(cnt, 0, (size_t)G * 4, stream);

    int ebk = (E + 255) / 256;
    hist_kernel<<<ebk, 256, 0, stream>>>(ei, deg, E);
    scan_kernel<<<1, 256, 0, stream>>>(deg, row_start, cursor, invdeg, nN);
    scatter_kernel<<<ebk, 256, 0, stream>>>(ei, ps, invdeg, cursor, edges, E);
    wprep_kernel<8, 32, 224><<<(32 * 224 + 255) / 256, 256, 0, stream>>>(w1, r1, wt1);
    wprep_kernel<32, 64, 832><<<(64 * 832 + 255) / 256, 256, 0, stream>>>(w2, r2, wt2);
    wprep_kernel<64, 64, 1664><<<(64 * 1664 + 255) / 256, 256, 0, stream>>>(w3, r3, wt3);

    // L1: Cin=8,Cout=32,T=32,KR=9   (AL 29.9KB)
    layer_kernel<8, 32, 32, 9><<<(nN + 31) / 32, 512, 0, stream>>>(
        x, wt1, b1, row_start, edges, h1, nN);
    // L2: Cin=32,Cout=64,T=16,KR=33 (AL 54.9KB)
    layer_kernel<32, 64, 16, 33><<<(nN + 15) / 16, 512, 0, stream>>>(
        h1, wt2, b2, row_start, edges, h2, nN);
    // L3: Cin=64,Cout=64,T=8,KR=67  (AL 55.7KB)
    layer_kernel<64, 64, 8, 67><<<(nN + 7) / 8, 512, 0, stream>>>(
        h2, wt3, b3, row_start, edges, h3, nN);

    pool_kernel<<<128, 256, 0, stream>>>(h3, batch, pooled, cnt, nN);
    head_kernel<<<1, 128, 0, stream>>>(pooled, cnt, fcw, fcb, outp, G);
}

// Round 8
// 502.086 us; speedup vs baseline: 4.3373x; 4.3373x over previous
//
#include <hip/hip_runtime.h>
#include <hip/hip_bf16.h>
#include <math.h>

// SplineCNN on MI355X — round 8.
// Prep: counting-sort 32B edge records {basis4*invdeg}{src,i00,dst,0} by dst.
// Layer stage-1 (per node, per wave): D[ch][k] = sum_e x[src_e][ch]*basis[e][k]
// via mfma_f32_16x16x32_bf16: A-frag = 8 per-lane register gathers from x,
// B-frag = per-node basis matrix B[32e][34k] built in LDS by 4-write scatter
// (conflict-free stride 17 dwords). D spills to acc[t][kk] (bf16, paired-slice
// layout, b64 writes over 4 consecutive ch). No atomics, no entry expansion.
// Phase B: split-K MFMA over kk=26*Cin (acc x Wt) + LDS reduce, bias+ELU.
// Activations bf16 between layers (2B gathers, no cvt in hot loop).

typedef __attribute__((ext_vector_type(8))) short bf16x8;
typedef __attribute__((ext_vector_type(4))) float f32x4;

__device__ __forceinline__ unsigned short f2bf(float f) {
    union { float f; unsigned u; } v; v.f = f;
    return (unsigned short)((v.u + 0x7fffu + ((v.u >> 16) & 1u)) >> 16);
}
__device__ __forceinline__ float bf2f(unsigned short h) {
    union { unsigned u; float f; } v; v.u = ((unsigned)h) << 16;
    return v.f;
}

// ---------------------------------------------------------------- preprocessing

__global__ void hist_kernel(const int* __restrict__ ei, int* __restrict__ deg, int E) {
    int e = blockIdx.x * blockDim.x + threadIdx.x;
    if (e < E) atomicAdd(&deg[ei[E + e]], 1);
}

__global__ __launch_bounds__(256) void scan_kernel(const int* __restrict__ deg,
                                                   int* __restrict__ row_start,
                                                   int* __restrict__ cursor,
                                                   float* __restrict__ invdeg, int n) {
    __shared__ int wsum[4];
    int tid = threadIdx.x, lane = tid & 63, wave = tid >> 6;
    int carry = 0;
    for (int base = 0; base < n; base += 2048) {
        int idx0 = base + tid * 8;
        int v[8], pre[8];
        int s = 0;
        #pragma unroll
        for (int u = 0; u < 8; ++u) {
            int id = idx0 + u;
            v[u] = (id < n) ? deg[id] : 0;
            pre[u] = s;
            s += v[u];
        }
        int inc = s;
        #pragma unroll
        for (int off = 1; off < 64; off <<= 1) {
            int t = __shfl_up(inc, off);
            if (lane >= off) inc += t;
        }
        if (lane == 63) wsum[wave] = inc;
        __syncthreads();
        int woff = 0;
        for (int w2 = 0; w2 < wave; ++w2) woff += wsum[w2];
        int tot = wsum[0] + wsum[1] + wsum[2] + wsum[3];
        int eb = carry + woff + inc - s;
        #pragma unroll
        for (int u = 0; u < 8; ++u) {
            int id = idx0 + u;
            if (id < n) {
                int rs = eb + pre[u];
                row_start[id] = rs;
                cursor[id] = rs;
                invdeg[id] = 1.0f / fmaxf((float)v[u], 1.0f);
            }
        }
        carry += tot;
        __syncthreads();
    }
    if (tid == 0) row_start[n] = carry;
}

// Edge record: 32B = float4 basis (pre-scaled by 1/deg[dst]) + {src, i00, dst, 0}
__global__ void scatter_kernel(const int* __restrict__ ei, const float* __restrict__ pseudo,
                               const float* __restrict__ invdeg, int* __restrict__ cursor,
                               float4* __restrict__ edges, int E) {
    int e = blockIdx.x * blockDim.x + threadIdx.x;
    if (e >= E) return;
    int src = ei[e], dst = ei[E + e];
    float p0 = pseudo[2 * e], p1 = pseudo[2 * e + 1];
    float v0 = fminf(fmaxf(p0, 0.f), 1.f) * 4.f;
    float v1 = fminf(fmaxf(p1, 0.f), 1.f) * 4.f;
    int k00 = min((int)floorf(v0), 3);
    int k01 = min((int)floorf(v1), 3);
    float f0 = v0 - (float)k00, f1 = v1 - (float)k01;
    float g0 = 1.f - f0, g1 = 1.f - f1;
    float sc = invdeg[dst];
    float4 b;
    b.x = g0 * g1 * sc;
    b.y = g0 * f1 * sc;
    b.z = f0 * g1 * sc;
    b.w = f0 * f1 * sc;
    int i00 = k00 * 5 + k01;
    int pos = atomicAdd(&cursor[dst], 1);
    edges[pos * 2] = b;
    float4 m;
    m.x = __int_as_float(src);
    m.y = __int_as_float(i00);
    m.z = __int_as_float(dst);
    m.w = 0.f;
    edges[pos * 2 + 1] = m;
}

// Wt[o][KW] bf16 from W[k][i][o] f32 (k=25 -> root), zero for kk >= 26*Cin.
template <int Cin, int Cout, int KW>
__global__ void wprep_kernel(const float* __restrict__ W, const float* __restrict__ root,
                             unsigned short* __restrict__ Wt) {
    int idx = blockIdx.x * 256 + threadIdx.x;
    if (idx >= Cout * KW) return;
    int o = idx / KW, kk = idx - o * KW;
    float v = 0.f;
    if (kk < 26 * Cin) {
        int k = kk / Cin, i = kk - k * Cin;
        v = (k < 25) ? W[(k * Cin + i) * Cout + o] : root[i * Cout + o];
    }
    Wt[idx] = f2bf(v);
}

// ---------------------------------------------------------------- fused layer

// acc element address for logical kk (paired-slice layout: 2 slices = 72 elems)
template <int ST>
__device__ __forceinline__ int pairaddr(int kk) {
    int slice = kk >> 5;
    return (slice >> 1) * 72 + (slice & 1) * 32 + (kk & 31);
}

template <int Cin, int Cout, bool F32IN>
__global__ __launch_bounds__(512, 4) void layer_kernel(
        const void* __restrict__ xin_, const unsigned short* __restrict__ Wt,
        const float* __restrict__ bias, const int* __restrict__ row_start,
        const float4* __restrict__ edges, unsigned short* __restrict__ xout,
        int nNodes) {
    constexpr int T = 16;
    constexpr int SLICES = (26 * Cin + 31) / 32;
    constexpr int NPAIR = (SLICES + 1) / 2;
    constexpr int ST = NPAIR * 72 + 8;          // ushort elems per node row
    constexpr int KWp = SLICES * 32;            // Wt row length
    constexpr int MT_S = (Cin + 15) / 16;       // stage-1 ch tiles (1,2,4)
    constexpr int NT_B = Cout / 16;             // phase-B o tiles (2 or 4)
    constexpr int W8 = 8 / NT_B;                // phase-B K-split ways
    constexpr int RS = Cout + 4;
    constexpr int BSZ = 32 * 34;                // basis matrix ushorts per wave

    __shared__ __align__(16) unsigned short lds[T * ST + 8 * BSZ];

    const int tid = threadIdx.x;
    const int node0 = blockIdx.x * T;
    const int wave = tid >> 6, lane = tid & 63;
    const int r16 = lane & 15, g8 = lane >> 4;
    const float* xf = (const float*)xin_;
    const unsigned short* xb = (const unsigned short*)xin_;

    // ---- zero acc + all B buffers
    {
        constexpr int NU4 = (T * ST + 8 * BSZ) / 8;
        uint4 z = make_uint4(0u, 0u, 0u, 0u);
        for (int p = tid; p < NU4; p += 512) ((uint4*)lds)[p] = z;
    }
    __syncthreads();
    // ---- self features at k=25
    for (int p = tid; p < T * Cin; p += 512) {
        int t = p / Cin, i = p - t * Cin;
        int n = node0 + t;
        if (n < nNodes) {
            unsigned short v = F32IN ? f2bf(xf[n * Cin + i]) : xb[n * Cin + i];
            lds[t * ST + pairaddr<ST>(25 * Cin + i)] = v;
        }
    }

    // ---- stage-1: per-node basis-GEMM, 2 nodes per wave
    unsigned short* Bw = lds + T * ST + wave * BSZ;
    for (int rr = 0; rr < 2; ++rr) {
        const int t = wave + 8 * rr;
        const int n = node0 + t;
        if (n >= nNodes) continue;
        const int eb = row_start[n], ee = row_start[n + 1];
        const int deg = ee - eb;
        f32x4 dacc[MT_S][2];
        #pragma unroll
        for (int mt = 0; mt < MT_S; ++mt)
            #pragma unroll
            for (int nt = 0; nt < 2; ++nt)
                dacc[mt][nt] = (f32x4){0.f, 0.f, 0.f, 0.f};

        for (int c = 0; c * 32 < deg; ++c) {
            const int base = eb + c * 32;
            // zero B (32x34 ushorts)
            {
                uint4 z = make_uint4(0u, 0u, 0u, 0u);
                #pragma unroll
                for (int q = 0; q < 3; ++q) {
                    int p = lane + q * 64;
                    if (p < BSZ / 8) *(uint4*)&Bw[p * 8] = z;
                }
            }
            // scatter basis (lanes 0..31 = edges of this chunk)
            if (lane < 32) {
                int e = base + lane;
                if (e < ee) {
                    float4 b4 = edges[2 * e];
                    int i00 = ((const int*)edges)[8 * e + 5];
                    Bw[lane * 34 + i00]     = f2bf(b4.x);
                    Bw[lane * 34 + i00 + 1] = f2bf(b4.y);
                    Bw[lane * 34 + i00 + 5] = f2bf(b4.z);
                    Bw[lane * 34 + i00 + 6] = f2bf(b4.w);
                }
            }
            // src indices for my 8 k-lane edges
            int srcs[8];
            #pragma unroll
            for (int j = 0; j < 8; ++j) {
                int e2 = min(base + g8 * 8 + j, ee - 1);
                srcs[j] = ((const int*)edges)[8 * e2 + 4];
            }
            // A-frags: 8 register gathers per ch-tile
            bf16x8 af[MT_S];
            #pragma unroll
            for (int mt = 0; mt < MT_S; ++mt) {
                int col = (Cin >= 16) ? (mt * 16 + r16) : min(r16, Cin - 1);
                #pragma unroll
                for (int j = 0; j < 8; ++j) {
                    unsigned short v = F32IN ? f2bf(xf[srcs[j] * Cin + col])
                                             : xb[srcs[j] * Cin + col];
                    af[mt][j] = (short)v;
                }
            }
            // B-frags + MFMA
            #pragma unroll
            for (int nt = 0; nt < 2; ++nt) {
                bf16x8 bf;
                #pragma unroll
                for (int j = 0; j < 8; ++j)
                    bf[j] = (short)Bw[(g8 * 8 + j) * 34 + nt * 16 + r16];
                #pragma unroll
                for (int mt = 0; mt < MT_S; ++mt)
                    dacc[mt][nt] = __builtin_amdgcn_mfma_f32_16x16x32_bf16(
                        af[mt], bf, dacc[mt][nt], 0, 0, 0);
            }
        }
        // spill D[ch][k] -> acc[t][k*Cin+ch] (b64 over 4 consecutive ch)
        #pragma unroll
        for (int nt = 0; nt < 2; ++nt) {
            int k = nt * 16 + r16;
            if (k < 25) {
                #pragma unroll
                for (int mt = 0; mt < MT_S; ++mt) {
                    int ch0 = mt * 16 + g8 * 4;
                    if (ch0 < Cin) {
                        unsigned p0 = (unsigned)f2bf(dacc[mt][nt][0]) |
                                      ((unsigned)f2bf(dacc[mt][nt][1]) << 16);
                        unsigned p1 = (unsigned)f2bf(dacc[mt][nt][2]) |
                                      ((unsigned)f2bf(dacc[mt][nt][3]) << 16);
                        uint2 pk = make_uint2(p0, p1);
                        *(uint2*)&lds[t * ST + pairaddr<ST>(k * Cin + ch0)] = pk;
                    }
                }
            }
        }
    }
    __syncthreads();

    // ---- phase B: acc x Wt, K-split W8 ways
    const int q = wave / NT_B;
    const int nt = wave % NT_B;
    f32x4 dacc = {0.f, 0.f, 0.f, 0.f};
    {
        const unsigned short* wp = Wt + (size_t)(nt * 16 + r16) * KWp;
        const unsigned short* ap = lds + r16 * ST;
        for (int s = q; s < SLICES; s += W8) {
            bf16x8 a8 = *(const bf16x8*)(ap + (s >> 1) * 72 + (s & 1) * 32 + g8 * 8);
            bf16x8 b8 = *(const bf16x8*)(wp + s * 32 + g8 * 8);
            dacc = __builtin_amdgcn_mfma_f32_16x16x32_bf16(a8, b8, dacc, 0, 0, 0);
        }
    }
    __syncthreads();
    float* red = (float*)lds;
    if (q > 0) {
        #pragma unroll
        for (int j = 0; j < 4; ++j)
            red[((q - 1) * T + g8 * 4 + j) * RS + nt * 16 + r16] = dacc[j];
    }
    __syncthreads();
    if (q == 0) {
        const int o = nt * 16 + r16;
        const float bo = bias[o];
        #pragma unroll
        for (int j = 0; j < 4; ++j) {
            int row = g8 * 4 + j;
            int n = node0 + row;
            if (n < nNodes) {
                float v = dacc[j] + bo;
                #pragma unroll
                for (int q2 = 1; q2 < W8; ++q2)
                    v += red[((q2 - 1) * T + row) * RS + o];
                v = (v > 0.f) ? v : expm1f(v);
                xout[n * Cout + o] = f2bf(v);
            }
        }
    }
}

// ---------------------------------------------------------------- pooling + head

__global__ void pool_kernel(const unsigned short* __restrict__ h, const int* __restrict__ batch,
                            float* __restrict__ pooled, float* __restrict__ cnt, int n) {
    int gw = (blockIdx.x * blockDim.x + threadIdx.x) >> 6;
    int lane = threadIdx.x & 63;
    int nw = (gridDim.x * blockDim.x) >> 6;
    int per = (n + nw - 1) / nw;
    int n0 = gw * per, n1 = min(n0 + per, n);
    if (n0 >= n1) return;
    int cur = batch[n0];
    float s = 0.f, c = 0.f;
    for (int nn = n0; nn < n1; ++nn) {
        int g = batch[nn];
        if (g != cur) {
            atomicAdd(&pooled[cur * 64 + lane], s);
            if (lane == 0) atomicAdd(&cnt[cur], c);
            s = 0.f; c = 0.f; cur = g;
        }
        s += bf2f(h[nn * 64 + lane]);
        c += 1.f;
    }
    atomicAdd(&pooled[cur * 64 + lane], s);
    if (lane == 0) atomicAdd(&cnt[cur], c);
}

__global__ __launch_bounds__(128) void head_kernel(const float* __restrict__ pooled,
                                                   const float* __restrict__ cnt,
                                                   const float* __restrict__ fcw,
                                                   const float* __restrict__ fcb,
                                                   float* __restrict__ outp, int G) {
    int g = threadIdx.x;
    if (g >= G) return;
    float inv = 1.f / fmaxf(cnt[g], 1.f);
    float l[30];
    float m = -1e30f;
    #pragma unroll
    for (int j = 0; j < 30; ++j) {
        float s = fcb[j];
        for (int i = 0; i < 64; ++i) s += pooled[g * 64 + i] * inv * fcw[i * 30 + j];
        l[j] = s;
        m = fmaxf(m, s);
    }
    float lse = 0.f;
    #pragma unroll
    for (int j = 0; j < 30; ++j) lse += expf(l[j] - m);
    lse = logf(lse);
    #pragma unroll
    for (int j = 0; j < 30; ++j) outp[g * 30 + j] = l[j] - m - lse;
}

// ---------------------------------------------------------------- launch

extern "C" void kernel_launch(void* const* d_in, const int* in_sizes, int n_in,
                              void* d_out, int out_size, void* d_ws, size_t ws_size,
                              hipStream_t stream) {
    const float* x = (const float*)d_in[0];
    const int* ei = (const int*)d_in[1];
    const float* ps = (const float*)d_in[2];
    const int* batch = (const int*)d_in[3];
    const float *w1 = (const float*)d_in[4], *r1 = (const float*)d_in[5], *b1 = (const float*)d_in[6];
    const float *w2 = (const float*)d_in[7], *r2 = (const float*)d_in[8], *b2 = (const float*)d_in[9];
    const float *w3 = (const float*)d_in[10], *r3 = (const float*)d_in[11], *b3 = (const float*)d_in[12];
    const float *fcw = (const float*)d_in[13], *fcb = (const float*)d_in[14];
    float* outp = (float*)d_out;

    const int nN = in_sizes[0] / 8;  // 50000
    const int E = in_sizes[1] / 2;   // 800000
    const int G = out_size / 30;     // 128

    char* wsb = (char*)d_ws;
    size_t off = 0;
    auto alloc = [&](size_t b) -> char* {
        char* p = wsb + off;
        off = (off + b + 255) & ~(size_t)255;
        return p;
    };
    int* deg = (int*)alloc((size_t)nN * 4);
    int* row_start = (int*)alloc((size_t)(nN + 1) * 4);
    int* cursor = (int*)alloc((size_t)nN * 4);
    float* invdeg = (float*)alloc((size_t)nN * 4);
    float4* edges = (float4*)alloc((size_t)E * 32);
    unsigned short* wt1 = (unsigned short*)alloc((size_t)32 * 224 * 2);
    unsigned short* wt2 = (unsigned short*)alloc((size_t)64 * 832 * 2);
    unsigned short* wt3 = (unsigned short*)alloc((size_t)64 * 1664 * 2);
    unsigned short* h1 = (unsigned short*)alloc((size_t)nN * 32 * 2);
    unsigned short* h2 = (unsigned short*)alloc((size_t)nN * 64 * 2);
    unsigned short* h3 = (unsigned short*)alloc((size_t)nN * 64 * 2);
    float* pooled = (float*)alloc((size_t)G * 64 * 4);
    float* cnt = (float*)alloc((size_t)G * 4);
    (void)ws_size;

    hipMemsetAsync(deg, 0, (size_t)nN * 4, stream);
    hipMemsetAsync(pooled, 0, (size_t)G * 64 * 4, stream);
    hipMemsetAsync(cnt, 0, (size_t)G * 4, stream);

    int ebk = (E + 255) / 256;
    hist_kernel<<<ebk, 256, 0, stream>>>(ei, deg, E);
    scan_kernel<<<1, 256, 0, stream>>>(deg, row_start, cursor, invdeg, nN);
    scatter_kernel<<<ebk, 256, 0, stream>>>(ei, ps, invdeg, cursor, edges, E);
    wprep_kernel<8, 32, 224><<<(32 * 224 + 255) / 256, 256, 0, stream>>>(w1, r1, wt1);
    wprep_kernel<32, 64, 832><<<(64 * 832 + 255) / 256, 256, 0, stream>>>(w2, r2, wt2);
    wprep_kernel<64, 64, 1664><<<(64 * 1664 + 255) / 256, 256, 0, stream>>>(w3, r3, wt3);

    int nb = (nN + 15) / 16;
    layer_kernel<8, 32, true><<<nb, 512, 0, stream>>>(
        x, wt1, b1, row_start, edges, h1, nN);
    layer_kernel<32, 64, false><<<nb, 512, 0, stream>>>(
        h1, wt2, b2, row_start, edges, h2, nN);
    layer_kernel<64, 64, false><<<nb, 512, 0, stream>>>(
        h2, wt3, b3, row_start, edges, h3, nN);

    pool_kernel<<<128, 256, 0, stream>>>(h3, batch, pooled, cnt, nN);
    head_kernel<<<1, 128, 0, stream>>>(pooled, cnt, fcw, fcb, outp, G);
}